// Round 1
// 1898.069 us; speedup vs baseline: 1.0019x; 1.0019x over previous
//
#include <hip/hip_runtime.h>

// AdEx Euler integration, fp32 port of the jax/numpy reference.
// T=40000 sequential steps; N=1024 neurons -> 16 producer waves on 16 CUs.
//
// MODEL (fits R1-R14): a lone in-order wave dispatches ~1 instr / 5.6 cyc
// REGARDLESS of dependency structure -> dispatch-slot-bound. Wall =
// 5.6 x producer-slots/step + stall amortization. Only levers: fewer
// producer slots, fewer stalls. Trajectory proven bit-stable under
// increment-level rounding changes (R5-R13, absmax EXACTLY 4.882812e-04).
//
// R11: minimal linear-recurrence step (11 VALU)             1858 us
// R13: producer/consumer wave split, 16-step LDS ring       1727 us
// R14: 2-steps/ds_write_b128, 32-step batches               1632 us (kernel)
// R15 (this): slot removal, math bit-identical:
//   - prep kernel materializes AD[t] = {Ar2_t, delta} float2 in workspace
//     (same f64-folded constants, same fmaf -> bit-identical values).
//     Producer prefetch: 16 bare global_load_dwordx4 / 32-step buffer
//     (0.5 slot/step, was 2.0) with NO dependent ALU -> vmcnt wait defers
//     one full PRODUCE (~2000 cyc cover), killing the in-prefetch stall.
//   - v_pk_fma_f32 (gfx950 packed fp32, op_sel broadcast) fuses the 4
//     linear FMAs into 2: state packed VW={V,w};
//       P1 = pk_fma({alpha,gamma},{V,V},{Ar2,delta})  op_sel_hi:[1,0,1]
//       P2 = pk_fma({ncRv,beta},{w,w},P1)             op_sel:[0,1,0]
//     Each half is the IDENTICAL IEEE fma of the scalar version.
//   - back-pressure poll every 2nd buffer (threshold pi-2 on 4-deep ring).
// Stream/step: 9 math + 0.5 AD load + 0.5 ds_write (+~0.6 loop) ~= 10.6
// slots vs R14's ~14.1. Predict ~1250-1380 us kernel.

typedef float v2f __attribute__((ext_vector_type(2)));

__device__ __forceinline__ float exp2_raw(float u) {
    float r;
    asm("v_exp_f32 %0, %1" : "=v"(r) : "v"(u));   // r = 2^u, ~1 ulp
    return r;
}

// s_waitcnt lgkmcnt(0) (0xC07F = vmcnt max, expcnt max, lgkmcnt 0).
#define LGKM0() __builtin_amdgcn_s_waitcnt(0xC07F)

// ---------------------------------------------------------------------------
// Prep: AD[k] = {Ar2_k, delta} for k in [0, T+32). Bit-identical constant
// folding to the producer's old in-loop computation (same f64 expressions,
// rounded once to f32; same fmaf on the same I value).
// ---------------------------------------------------------------------------
__global__ void __launch_bounds__(256) adex_prep_kernel(
    const float* __restrict__ I_ext,
    const float* __restrict__ p_V_rest,
    const float* __restrict__ p_R,
    const float* __restrict__ p_tau,
    const float* __restrict__ p_tau_w,
    const float* __restrict__ p_a,
    float2* __restrict__ AD, int T)
{
#pragma clang fp contract(off)
    int k = blockIdx.x * 256 + threadIdx.x;
    if (k >= T + 32) return;

    const float V_rest = *p_V_rest;
    const float R      = *p_R;
    const float tau    = *p_tau;
    const float tau_w  = *p_tau_w;
    const float a      = *p_a;
    const float dt     = 5e-5f;

    const double dcv = (double)dt / (double)tau;
    const double dcw = (double)dt / (double)tau_w;

    const float cRI   = (float)(dcv * (double)R);
    const float cVr2  = (float)(dcv * (double)V_rest);
    const float delta = (float)(-(double)a * dcw * (double)V_rest);

    int ki = (k <= T + 4) ? k : (T + 4);      // tail entries never consumed
    AD[k] = make_float2(fmaf(cRI, I_ext[ki], cVr2), delta);
}

// ---------------------------------------------------------------------------
// Main producer/consumer kernel.
// ---------------------------------------------------------------------------
__global__ void __launch_bounds__(128, 1) adex_pc_kernel(
    const float* __restrict__ V0,
    const float* __restrict__ w0,
    const float* __restrict__ p_V_reset,
    const float* __restrict__ p_V_T,
    const float* __restrict__ p_V_thres,
    const float* __restrict__ p_delta_T,
    const float* __restrict__ p_R,
    const float* __restrict__ p_tau,
    const float* __restrict__ p_tau_w,
    const float* __restrict__ p_a,
    const float* __restrict__ p_b,
    const float4* __restrict__ AD4,      // workspace: {Ar2,delta} pairs, 2/quad
    float* __restrict__ out,
    int T, int N)
{
#pragma clang fp contract(off)
    // Ring of 4 buffers x 16 step-pairs x 64 lanes x float4 = 64 KiB.
    __shared__ float4 stage[4][16][64];
    __shared__ int    flags[2];          // [0]=produced bufs, [1]=consumed

    const int tid   = threadIdx.x;
    const int l     = tid & 63;
    const int wave  = tid >> 6;
    const int nbase = blockIdx.x * 64;   // N % 64 == 0

    volatile int* vflags = (volatile int*)flags;
    if (tid < 2) flags[tid] = 0;
    __syncthreads();                     // once, at kernel start only

    const int NB = T >> 5;               // 32-step buffers (T % 64 == 0)

    if (wave == 0) {
        // ---------------- producer: the serial recurrence ----------------
        const float V_reset = *p_V_reset;
        const float V_T     = *p_V_T;
        const float V_thres = *p_V_thres;
        const float delta_T = *p_delta_T;
        const float R       = *p_R;
        const float tau     = *p_tau;
        const float tau_w   = *p_tau_w;
        const float a       = *p_a;
        const float b       = *p_b;
        const float dt      = 5e-5f;

        // Constants folded in f64, rounded once to f32 (bit-neutral class).
        const double dT  = (double)delta_T;
        const double dcv = (double)dt / (double)tau;
        const double dcw = (double)dt / (double)tau_w;
        const double l2e = 1.4426950408889634;

        const float c_exp = (float)(l2e / dT);
        const float c2    = (float)(log2(dT * dcv) - (double)V_T * (l2e / dT));
        const float alpha = (float)(1.0 - dcv);
        const float ncRv  = (float)(-dcv * (double)R);
        const float beta  = (float)(1.0 - dcw);
        const float gamma = (float)((double)a * dcw);

        // Packed coefficient pairs for v_pk_fma_f32.
        v2f cAG; cAG.x = alpha; cAG.y = gamma;
        v2f cNB; cNB.x = ncRv;  cNB.y = beta;

        // Packed state {V, w}.
        v2f VW;
        VW.x = V0[nbase + l];
        VW.y = w0[nbase + l];

        // Pure math step, 9 VALU slots; every fp op bit-identical to R14:
        //   P1.lo = fma(alpha,V,Ar2)   P1.hi = fma(gamma,V,delta)
        //   P2.lo = fma(ncRv,w,P1.lo)  P2.hi = fma(beta,w,P1.hi)
        //   ex3 = 2^fma(V,c_exp,c2); Vn = P2.lo+ex3; spike sel; wns = P2.hi+b
#define ADEX_MATH(ADP)                                                    \
        {                                                                 \
            v2f P1, P2;                                                   \
            asm("v_pk_fma_f32 %0, %1, %2, %3 op_sel:[0,0,0] op_sel_hi:[1,0,1]" \
                : "=v"(P1) : "v"(cAG), "v"(VW), "v"(ADP));                \
            asm("v_pk_fma_f32 %0, %1, %2, %3 op_sel:[0,1,0] op_sel_hi:[1,1,1]" \
                : "=v"(P2) : "v"(cNB), "v"(VW), "v"(P1));                 \
            float ex3 = exp2_raw(fmaf(VW.x, c_exp, c2));                  \
            float Vn  = P2.x + ex3;                                       \
            bool  spike = VW.x > V_thres;                                 \
            float wns = P2.y + b;                                         \
            VW.x = spike ? V_reset : Vn;                                  \
            VW.y = spike ? wns : P2.y;                                    \
        }

        // One 32-step buffer: 16 pairs, each {quad AD, 2 math steps, 1
        // ds_write_b128}. Slot base computed once; per-pair DS offset is a
        // compile-time imm. Back-pressure polled every 2nd buffer: ring is
        // 4 deep, producing pi needs consumed >= pi-3; checking >= pi-2 at
        // even pi covers pi and pi+1.
#define PRODUCE(ARR4)                                               \
        {                                                           \
            if (!(pi & 1)) {                                        \
                while (vflags[1] < pi - 2)                          \
                    __builtin_amdgcn_s_sleep(2);                    \
            }                                                       \
            asm volatile("" ::: "memory");                          \
            float4* sb = &stage[pi & 3][0][l];                      \
            _Pragma("unroll")                                       \
            for (int s = 0; s < 16; ++s) {                          \
                float4 q = ARR4[s];                                 \
                v2f ad0; ad0.x = q.x; ad0.y = q.y;                  \
                v2f ad1; ad1.x = q.z; ad1.y = q.w;                  \
                v2f Sa = VW;                                        \
                ADEX_MATH(ad0);                                     \
                v2f Sb = VW;                                        \
                ADEX_MATH(ad1);                                     \
                sb[s * 64] = make_float4(Sa.x, Sa.y, Sb.x, Sb.y);   \
            }                                                       \
            LGKM0();                                                \
            asm volatile("" ::: "memory");                          \
            ++pi;                                                   \
            vflags[0] = pi;                                         \
        }

        // Double-buffered AD quads: 16 x dwordx4 per 32-step buffer, no
        // dependent ALU in the prefetch (vmcnt defers to first use, one
        // full PRODUCE later). AD is filled to T+32 so no tail clamp.
        float4 A4[16], B4[16];
#pragma unroll
        for (int j = 0; j < 16; ++j) A4[j] = AD4[j];

        int pi = 0;
        for (int kb = 0; kb < T; kb += 64) {
            const float4* nb = AD4 + (kb >> 1) + 16;   // steps kb+32..kb+63
#pragma unroll
            for (int j = 0; j < 16; ++j) B4[j] = nb[j];

            PRODUCE(A4);

            const float4* na = AD4 + (kb >> 1) + 32;   // steps kb+64..kb+95
#pragma unroll
            for (int j = 0; j < 16; ++j) A4[j] = na[j];

            PRODUCE(B4);
        }
#undef PRODUCE
#undef ADEX_MATH
    } else {
        // ---------------- consumer: drain LDS -> global ----------------
        float* outV = out + nbase + l;
        float* outW = out + (size_t)T * N + nbase + l;

        for (int ci = 0; ci < NB; ++ci) {
            while (vflags[0] < ci + 1) __builtin_amdgcn_s_sleep(2);
            asm volatile("" ::: "memory");
            const float4* cb = &stage[ci & 3][0][l];
#pragma unroll
            for (int s = 0; s < 16; ++s) {
                float4 q = cb[s * 64];
                outV[0] = q.x;          // step 2s
                outW[0] = q.y;
                outV[N] = q.z;          // step 2s+1
                outW[N] = q.w;
                outV += 2 * N;
                outW += 2 * N;
            }
            // LDS reads retired (store data deps forced waits); slot free.
            asm volatile("" ::: "memory");
            vflags[1] = ci + 1;
        }
    }
}

// Fallback: R11-style single-wave kernel for shapes that don't meet the
// producer/consumer preconditions (N%64, T%64, workspace size).
__global__ void __launch_bounds__(64, 1) adex_fallback_kernel(
    const float* __restrict__ I_ext,
    const float* __restrict__ V0,
    const float* __restrict__ w0,
    const float* __restrict__ p_V_rest,
    const float* __restrict__ p_V_reset,
    const float* __restrict__ p_V_T,
    const float* __restrict__ p_V_thres,
    const float* __restrict__ p_delta_T,
    const float* __restrict__ p_R,
    const float* __restrict__ p_tau,
    const float* __restrict__ p_tau_w,
    const float* __restrict__ p_a,
    const float* __restrict__ p_b,
    float* __restrict__ out,
    int T, int N)
{
#pragma clang fp contract(off)
    const int l     = threadIdx.x;
    const int nbase = blockIdx.x * 64;
    int n = nbase + l;
    if (n >= N) n = N - 1;

    const float V_rest  = *p_V_rest;
    const float V_reset = *p_V_reset;
    const float V_T     = *p_V_T;
    const float V_thres = *p_V_thres;
    const float delta_T = *p_delta_T;
    const float R       = *p_R;
    const float tau     = *p_tau;
    const float tau_w   = *p_tau_w;
    const float a       = *p_a;
    const float b       = *p_b;
    const float dt      = 5e-5f;

    const double dT  = (double)delta_T;
    const double dcv = (double)dt / (double)tau;
    const double dcw = (double)dt / (double)tau_w;
    const double l2e = 1.4426950408889634;

    const float c_exp = (float)(l2e / dT);
    const float c2    = (float)(log2(dT * dcv) - (double)V_T * (l2e / dT));
    const float alpha = (float)(1.0 - dcv);
    const float ncRv  = (float)(-dcv * (double)R);
    const float beta  = (float)(1.0 - dcw);
    const float gamma = (float)((double)a * dcw);
    const float delta = (float)(-(double)a * dcw * (double)V_rest);
    const float cRI   = (float)(dcv * (double)R);
    const float cVr2  = (float)(dcv * (double)V_rest);

    float V = V0[n];
    float w = w0[n];

    float* outVb = out + nbase;
    float* outWb = out + (size_t)T * N + nbase;

#define ADEX_STEP(Ar2_k)                                            \
    {                                                               \
        outVb[l] = V;                                               \
        outWb[l] = w;                                               \
        outVb += N;                                                 \
        outWb += N;                                                 \
        float ex3 = exp2_raw(fmaf(V, c_exp, c2));                   \
        float m1  = fmaf(alpha, V, (Ar2_k));                        \
        float m2  = fmaf(ncRv, w, m1);                              \
        float Vn  = m2 + ex3;                                       \
        float t2  = fmaf(gamma, V, delta);                          \
        float wn  = fmaf(beta, w, t2);                              \
        bool  spike = V > V_thres;                                  \
        float wns = wn + b;                                         \
        Vn = spike ? V_reset : Vn;                                  \
        wn = spike ? wns : wn;                                      \
        V = Vn;                                                     \
        w = wn;                                                     \
    }

    float A[16], B[16];
#pragma unroll
    for (int j = 0; j < 16; ++j) A[j] = fmaf(cRI, I_ext[j], cVr2);

    for (int kb = 0; kb < T; kb += 32) {
#pragma unroll
        for (int j = 0; j < 16; ++j)
            B[j] = fmaf(cRI, I_ext[kb + 16 + j], cVr2);
#pragma unroll
        for (int j = 0; j < 16; ++j) ADEX_STEP(A[j]);
        {
            int pb = kb + 32;
            if (pb > T - 11) pb = T - 11;
#pragma unroll
            for (int j = 0; j < 16; ++j)
                A[j] = fmaf(cRI, I_ext[pb + j], cVr2);
        }
#pragma unroll
        for (int j = 0; j < 16; ++j) ADEX_STEP(B[j]);
    }
#undef ADEX_STEP
}

extern "C" void kernel_launch(void* const* d_in, const int* in_sizes, int n_in,
                              void* d_out, int out_size, void* d_ws, size_t ws_size,
                              hipStream_t stream) {
    const float* I_ext = (const float*)d_in[0];
    const float* V0    = (const float*)d_in[1];
    const float* w0    = (const float*)d_in[2];

    const int N = in_sizes[1];          // 1024 (multiple of 64)
    const int T = out_size / (2 * N);   // 40000 (multiple of 64)

    const size_t ws_need = (size_t)(T + 32) * sizeof(float2);

    if ((N % 64 == 0) && (T % 64 == 0) && d_ws != nullptr && ws_size >= ws_need) {
        adex_prep_kernel<<<(T + 32 + 255) / 256, 256, 0, stream>>>(
            I_ext,
            (const float*)d_in[3],      // V_rest
            (const float*)d_in[8],      // R
            (const float*)d_in[9],      // tau
            (const float*)d_in[10],     // tau_w
            (const float*)d_in[11],     // a
            (float2*)d_ws, T);
        adex_pc_kernel<<<N / 64, 128, 0, stream>>>(
            V0, w0,
            (const float*)d_in[4],      // V_reset
            (const float*)d_in[5],      // V_T
            (const float*)d_in[6],      // V_thres
            (const float*)d_in[7],      // delta_T
            (const float*)d_in[8],      // R
            (const float*)d_in[9],      // tau
            (const float*)d_in[10],     // tau_w
            (const float*)d_in[11],     // a
            (const float*)d_in[12],     // b
            (const float4*)d_ws,
            (float*)d_out, T, N);
    } else {
        adex_fallback_kernel<<<(N + 63) / 64, 64, 0, stream>>>(
            I_ext, V0, w0,
            (const float*)d_in[3], (const float*)d_in[4], (const float*)d_in[5],
            (const float*)d_in[6], (const float*)d_in[7], (const float*)d_in[8],
            (const float*)d_in[9], (const float*)d_in[10], (const float*)d_in[11],
            (const float*)d_in[12], (float*)d_out, T, N);
    }
}